// Round 9
// baseline (353.370 us; speedup 1.0000x reference)
//
#include <hip/hip_runtime.h>
#include <hip/hip_bf16.h>

#define B_TOT 2048
#define N_CAP 200
#define D_DIM 256
#define NT    512
#define NW    8               // waves per block
#define CPW   25              // capsules per wave (200/8, exact)

__device__ __forceinline__ float bf_lo(unsigned u) { return __uint_as_float(u << 16); }
__device__ __forceinline__ float bf_hi(unsigned u) { return __uint_as_float(u & 0xffff0000u); }

__device__ __forceinline__ float wave_sum(float v) {
#pragma unroll
    for (int off = 32; off; off >>= 1) v += __shfl_xor(v, off);
    return v;
}
// wave-uniform value -> SGPR (cuts VGPR pressure; value identical in all lanes)
__device__ __forceinline__ float rfl(float x) {
    return __uint_as_float(__builtin_amdgcn_readfirstlane(__float_as_uint(x)));
}

// Design point: the allocator ALWAYS picks 64 VGPR for 512-thr blocks here
// (R3/R4/R8: attributes don't move it; exceeding 64 = scratch spill traffic).
// So fit 64 for real: u[25]=50 persistent + depth-2 load chunks (8 in flight)
// + all wave-uniform scalars in SGPRs via readfirstlane. 64 VGPR -> 8 waves/EU
// -> 4 blocks/CU co-resident; TLP (32 waves x 2 loads) hides HBM latency, and
// other blocks' loads hide this block's routing phase.
__global__ __launch_bounds__(NT, 8)
void dyr_kernel(
        const float* __restrict__ embeds,
        const float* __restrict__ weights,
        float* __restrict__ out_v,
        float* __restrict__ out_c)
{
    __shared__ float s_part[NW][D_DIM];   // 8 KB
    __shared__ float red[NW];
    __shared__ float b_lds[N_CAP];        // routing logits; wave w owns [w + 8i]
    __shared__ float e_lds[N_CAP];        // exp(b) staging, rewritten each iter

    const int b    = blockIdx.x;
    const int t    = threadIdx.x;
    const int wave = t >> 6;
    const int lane = t & 63;

    // ---- init logits ----
    if (t < N_CAP) b_lds[t] = weights[(size_t)b * N_CAP + t];

    // ---- Load embeds ONCE, normalize per capsule, keep u_hat in REGISTERS.
    // wave w, lane l holds capsule n = w + 8i, dims [4l, 4l+4), packed bf16.
    // Chunks of 2 in-flight float4s; sched_barrier between chunks bounds the
    // register peak (TLP across 32 resident waves hides the load latency). ----
    const float* eb = embeds + (size_t)b * (N_CAP * D_DIM) + lane * 4;

    uint2 u[CPW];   // 50 VGPRs
#pragma unroll
    for (int cc = 0; cc < 13; ++cc) {     // 25 = 12*2 + 1
        const int base = cc * 2;
        const int cnt  = (cc == 12) ? 1 : 2;
        float4 xs[2];
#pragma unroll
        for (int j = 0; j < 2; ++j) {
            if (j < cnt)
                xs[j] = *reinterpret_cast<const float4*>(eb + (wave + (base + j) * NW) * D_DIM);
        }
#pragma unroll
        for (int j = 0; j < 2; ++j) {
            if (j < cnt) {
                const float4 x = xs[j];
                float ss = fmaf(x.x, x.x, fmaf(x.y, x.y, fmaf(x.z, x.z, x.w * x.w)));
                ss = wave_sum(ss);
                const float inv = rfl(1.0f / fmaxf(sqrtf(ss), 1e-12f));   // SGPR
                union { __hip_bfloat16 h[4]; uint2 q; } pk;
                pk.h[0] = __float2bfloat16(x.x * inv);
                pk.h[1] = __float2bfloat16(x.y * inv);
                pk.h[2] = __float2bfloat16(x.z * inv);
                pk.h[3] = __float2bfloat16(x.w * inv);
                u[base + j] = pk.q;
            }
        }
        __builtin_amdgcn_sched_barrier(0);   // bound in-flight regs between chunks
    }

    // ---- 3 routing iterations: 2 barriers each ----
    for (int r = 0; r < 3; ++r) {
        // owner-wave exp: lane i (<25) handles capsule wave+8i.
        // (no max-subtraction: |b| <= |w|+2 <= ~8 -> fp32 exp safe)
        float ev = 0.f;
        if (lane < CPW) {
            ev = __expf(b_lds[wave + NW * lane]);
            e_lds[wave + NW * lane] = ev;
        }
        const float esp = wave_sum(ev);
        if (lane == 0) red[wave] = esp;
        __syncthreads();                       // B1: red[], e_lds visible

        float es = 0.f;
#pragma unroll
        for (int w = 0; w < NW; ++w) es += red[w];
        const float cs = rfl((float)N_CAP / es);   // SGPR

        // einsum partial: acc = cs * sum_i e_i * u_i (own capsules, e broadcast)
        float4 acc = make_float4(0.f, 0.f, 0.f, 0.f);
#pragma unroll
        for (int i = 0; i < CPW; ++i) {
            const float ei = e_lds[wave + NW * i];   // wave-uniform ds broadcast
            acc.x = fmaf(ei, bf_lo(u[i].x), acc.x);
            acc.y = fmaf(ei, bf_hi(u[i].x), acc.y);
            acc.z = fmaf(ei, bf_lo(u[i].y), acc.z);
            acc.w = fmaf(ei, bf_hi(u[i].y), acc.w);
        }
        acc.x *= cs; acc.y *= cs; acc.z *= cs; acc.w *= cs;
        *reinterpret_cast<float4*>(&s_part[wave][lane * 4]) = acc;

        if (r == 2 && t < N_CAP)               // c = e * N/es, coalesced
            out_c[(size_t)b * N_CAP + t] = e_lds[t] * cs;
        __syncthreads();                       // B2: s_part visible

        // cross-wave reduce + squash, computed redundantly per wave
        float4 sd = make_float4(0.f, 0.f, 0.f, 0.f);
#pragma unroll
        for (int w = 0; w < NW; ++w) {
            const float4 p = *reinterpret_cast<const float4*>(&s_part[w][lane * 4]);
            sd.x += p.x; sd.y += p.y; sd.z += p.z; sd.w += p.w;
        }
        float ssn = fmaf(sd.x, sd.x, fmaf(sd.y, sd.y, fmaf(sd.z, sd.z, sd.w * sd.w)));
        ssn = rfl(wave_sum(ssn));
        const float scale = ssn / (1.0f + ssn) * rsqrtf(ssn + 1e-9f);   // SGPR math
        const float4 vv = make_float4(scale * sd.x, scale * sd.y,
                                      scale * sd.z, scale * sd.w);

        if (r == 2) {
            if (wave == 0)
                *reinterpret_cast<float4*>(&out_v[(size_t)b * D_DIM + lane * 4]) = vv;
        } else {
            // agreement: b[n] += u_hat[n].v ; owner-wave slots (lane 0 writes),
            // next iteration's exp reads are same-wave -> no barrier needed.
#pragma unroll
            for (int i = 0; i < CPW; ++i) {
                float p = fmaf(bf_lo(u[i].x), vv.x,
                          fmaf(bf_hi(u[i].x), vv.y,
                          fmaf(bf_lo(u[i].y), vv.z,
                               bf_hi(u[i].y) * vv.w)));
                p = wave_sum(p);
                if (lane == 0) b_lds[wave + NW * i] += p;
            }
        }
    }
}

extern "C" void kernel_launch(void* const* d_in, const int* in_sizes, int n_in,
                              void* d_out, int out_size, void* d_ws, size_t ws_size,
                              hipStream_t stream) {
    const float* embeds  = (const float*)d_in[0];
    const float* weights = (const float*)d_in[1];
    float* out   = (float*)d_out;
    float* out_v = out;                                  // [2048, 256]
    float* out_c = out + (size_t)B_TOT * D_DIM;          // [2048, 200]

    dyr_kernel<<<B_TOT, NT, 0, stream>>>(embeds, weights, out_v, out_c);
}

// Round 10
// 162.130 us; speedup vs baseline: 2.1796x; 2.1796x over previous
//
#include <hip/hip_runtime.h>
#include <hip/hip_bf16.h>

#define B_TOT 2048
#define N_CAP 200
#define D_DIM 256
#define NT    512
#define NW    8               // waves per block
#define CPW   25              // capsules per wave (200/8, exact)

__device__ __forceinline__ float bf_lo(unsigned u) { return __uint_as_float(u << 16); }
__device__ __forceinline__ float bf_hi(unsigned u) { return __uint_as_float(u & 0xffff0000u); }

__device__ __forceinline__ float wave_sum(float v) {
#pragma unroll
    for (int off = 32; off; off >>= 1) v += __shfl_xor(v, off);
    return v;
}

// Block sum WITHOUT leading barrier: caller must guarantee a __syncthreads()
// executed between the previous read of red[] and this call (WAR safety).
__device__ __forceinline__ float block_sum_nb(float v, float* red, int wave, int lane) {
    v = wave_sum(v);
    if (lane == 0) red[wave] = v;
    __syncthreads();
    float s = 0.f;
#pragma unroll
    for (int i = 0; i < NW; ++i) s += red[i];
    return s;
}

// Anchor = R2's exact structure (170us; the ONLY config the allocator handles
// well: LB(512,4), u[25] in regs, 5x5 load chunks, unfused loops). Deltas:
//  1) fold-norm: store RAW x bf16; inv_n in LDS; einsum weight w_n = c_n*inv_n,
//     agreement dot scaled by inv_n. Deletes load-phase inv-mul + cs rescale.
//  2) no block_max (|b|<=~8, fp32 exp safe; validated R8).
//  3) block_sum without leading barrier (external barriers provide WAR order).
// DO NOT: fuse agreement+einsum (R3/R4: 64-VGPR spill), LB(...,8) (R9: 32
// VGPR), per-capsule sched_barrier (R6: depth-1 loads), LDS-split u (R7).
__global__ __launch_bounds__(NT, 4)
void dyr_kernel(const float* __restrict__ embeds,
                const float* __restrict__ weights,
                float* __restrict__ out_v,
                float* __restrict__ out_c)
{
    __shared__ float s_part[NW][D_DIM];   // 8 KB
    __shared__ float red[NW];
    __shared__ float b_lds[N_CAP];        // routing logits
    __shared__ float w_lds[N_CAP];        // einsum weights c_n * inv_n
    __shared__ float inv_lds[N_CAP];      // 1 / max(||x_n||, 1e-12)
    __shared__ float v_lds[D_DIM];

    const int b    = blockIdx.x;
    const int t    = threadIdx.x;
    const int wave = t >> 6;
    const int lane = t & 63;

    // ---- init logits ----
    if (t < N_CAP) b_lds[t] = weights[(size_t)b * N_CAP + t];

    // ---- Load embeds ONCE; keep RAW x in bf16 registers; norms to LDS.
    // wave w, lane l holds capsule n = w + 8i, dims [4l, 4l+4).
    // 5 chunks x 5 in-flight float4 loads (R2's exact schedule). ----
    const float* eb = embeds + (size_t)b * (N_CAP * D_DIM) + lane * 4;

    uint2 u[CPW];   // 50 VGPRs, raw x packed bf16
#pragma unroll
    for (int cc = 0; cc < 5; ++cc) {
        float4 xs[5];
#pragma unroll
        for (int j = 0; j < 5; ++j) {
            const int n = wave + (cc * 5 + j) * NW;
            xs[j] = *reinterpret_cast<const float4*>(eb + n * D_DIM);
        }
#pragma unroll
        for (int j = 0; j < 5; ++j) {
            const float4 x = xs[j];
            float ss = fmaf(x.x, x.x, fmaf(x.y, x.y, fmaf(x.z, x.z, x.w * x.w)));
            ss = wave_sum(ss);
            if (lane == 0)
                inv_lds[wave + (cc * 5 + j) * NW] = 1.0f / fmaxf(sqrtf(ss), 1e-12f);
            union { __hip_bfloat16 h[4]; uint2 q; } pk;
            pk.h[0] = __float2bfloat16(x.x);
            pk.h[1] = __float2bfloat16(x.y);
            pk.h[2] = __float2bfloat16(x.z);
            pk.h[3] = __float2bfloat16(x.w);
            u[cc * 5 + j] = pk.q;
        }
    }
    __syncthreads();   // inv_lds visible; WAR-guard for first block_sum_nb

    // ---- 3 routing iterations ----
    for (int r = 0; r < 3; ++r) {
        // softmax denominator (no max-subtraction; |b| <= ~8)
        const float e  = (t < N_CAP) ? __expf(b_lds[t]) : 0.0f;
        const float es = block_sum_nb(e, red, wave, lane);
        const float cs = (float)N_CAP / es;
        if (t < N_CAP) {
            const float cv = e * cs;             // c_n = softmax * N
            w_lds[t] = cv * inv_lds[t];          // einsum weight (norm folded)
            if (r == 2) out_c[(size_t)b * N_CAP + t] = cv;
        }
        __syncthreads();                          // w_lds visible

        // einsum partial: acc = sum_i w_i * x_i  (own capsules, w broadcast)
        float4 acc = make_float4(0.f, 0.f, 0.f, 0.f);
#pragma unroll
        for (int i = 0; i < CPW; ++i) {
            const float wn = w_lds[wave + NW * i];   // wave-uniform broadcast
            acc.x = fmaf(wn, bf_lo(u[i].x), acc.x);
            acc.y = fmaf(wn, bf_hi(u[i].x), acc.y);
            acc.z = fmaf(wn, bf_lo(u[i].y), acc.z);
            acc.w = fmaf(wn, bf_hi(u[i].y), acc.w);
        }
        *reinterpret_cast<float4*>(&s_part[wave][lane * 4]) = acc;
        __syncthreads();                          // s_part visible; WAR-guard

        // cross-wave reduce + squash (R2's exact shape)
        float sd = 0.f;
        if (t < D_DIM) {
#pragma unroll
            for (int w = 0; w < NW; ++w) sd += s_part[w][t];
        }
        const float ssn = block_sum_nb(sd * sd, red, wave, lane);
        if (t < D_DIM) {
            const float scale = ssn / (1.0f + ssn) * rsqrtf(ssn + 1e-9f);
            const float vd = scale * sd;
            v_lds[t] = vd;
            if (r == 2) out_v[(size_t)b * D_DIM + t] = vd;
        }

        if (r < 2) {
            __syncthreads();                      // v_lds visible; WAR-guard
            const float4 vv = *reinterpret_cast<const float4*>(&v_lds[lane * 4]);
            // agreement: b_n += (x_n . v) * inv_n
#pragma unroll
            for (int i = 0; i < CPW; ++i) {
                float p = fmaf(bf_lo(u[i].x), vv.x,
                          fmaf(bf_hi(u[i].x), vv.y,
                          fmaf(bf_lo(u[i].y), vv.z,
                               bf_hi(u[i].y) * vv.w)));
                p = wave_sum(p);
                if (lane == 0) {
                    const int n = wave + NW * i;
                    b_lds[n] += p * inv_lds[n];
                }
            }
            __syncthreads();                      // b_lds visible for next iter
        }
    }
}

extern "C" void kernel_launch(void* const* d_in, const int* in_sizes, int n_in,
                              void* d_out, int out_size, void* d_ws, size_t ws_size,
                              hipStream_t stream) {
    const float* embeds  = (const float*)d_in[0];
    const float* weights = (const float*)d_in[1];
    float* out   = (float*)d_out;
    float* out_v = out;                                  // [2048, 256]
    float* out_c = out + (size_t)B_TOT * D_DIM;          // [2048, 200]

    dyr_kernel<<<B_TOT, NT, 0, stream>>>(embeds, weights, out_v, out_c);
}